// Round 1
// baseline (125.009 us; speedup 1.0000x reference)
//
#include <hip/hip_runtime.h>
#include <math.h>

#define NTOK 16384
#define HDIM 2048
#define NEXP 64
#define TOPK 6
#define TB   64          // tokens per block
#define CH   128         // h-chunk
#define NCH  (HDIM / CH) // 16

// XOR-swizzle float4 blocks within a row so strided row reads spread banks.
__device__ __forceinline__ int swz(int row, int h) {
    return row * CH + (h ^ (((row >> 2) & 7) << 2));
}

__global__ __launch_bounds__(256, 1) void moe_gate_kernel(
        const float* __restrict__ x,
        const float* __restrict__ w,
        float* __restrict__ out)
{
    __shared__ float xs[TB * CH];          // 32 KB, swizzled
    __shared__ float ws[NEXP * CH];        // 32 KB, swizzled
    __shared__ float lg[TB * (NEXP + 1)];  // logits, +1 pad

    const int tid   = threadIdx.x;
    const int tbase = blockIdx.x * TB;

    const int ge   = tid & 15;   // expert group: experts 4*ge..4*ge+3
    const int gt   = tid >> 4;   // token  group: tokens  4*gt..4*gt+3
    const int col4 = tid & 31;   // staging: float4 column
    const int row0 = tid >> 5;   // staging: base row (0..7)

    // acc[r][s] holds 4 partial sums (h mod 4 lanes) for (token 4*gt+r, expert 4*ge+s)
    float4 acc[4][4];
    #pragma unroll
    for (int r = 0; r < 4; ++r)
        #pragma unroll
        for (int s = 0; s < 4; ++s)
            acc[r][s] = make_float4(0.f, 0.f, 0.f, 0.f);

    for (int ck = 0; ck < NCH; ++ck) {
        // ---- stage x-tile and w-tile (coalesced global float4 -> swizzled LDS) ----
        #pragma unroll
        for (int it = 0; it < 8; ++it) {
            const int row = row0 + 8 * it;
            const float4 xv = *(const float4*)&x[(size_t)(tbase + row) * HDIM + ck * CH + 4 * col4];
            *(float4*)&xs[swz(row, 4 * col4)] = xv;
            const float4 wv = *(const float4*)&w[(size_t)row * HDIM + ck * CH + 4 * col4];
            *(float4*)&ws[swz(row, 4 * col4)] = wv;
        }
        __syncthreads();

        // ---- register-tile FMA: 4 tokens x 4 experts x 4 h per step ----
        #pragma unroll 8
        for (int h0 = 0; h0 < CH; h0 += 4) {
            float4 xv[4], wv[4];
            #pragma unroll
            for (int r = 0; r < 4; ++r)
                xv[r] = *(const float4*)&xs[swz(4 * gt + r, h0)];
            #pragma unroll
            for (int s = 0; s < 4; ++s)
                wv[s] = *(const float4*)&ws[swz(4 * ge + s, h0)];
            #pragma unroll
            for (int r = 0; r < 4; ++r)
                #pragma unroll
                for (int s = 0; s < 4; ++s) {
                    acc[r][s].x = fmaf(xv[r].x, wv[s].x, acc[r][s].x);
                    acc[r][s].y = fmaf(xv[r].y, wv[s].y, acc[r][s].y);
                    acc[r][s].z = fmaf(xv[r].z, wv[s].z, acc[r][s].z);
                    acc[r][s].w = fmaf(xv[r].w, wv[s].w, acc[r][s].w);
                }
        }
        __syncthreads();
    }

    // ---- combine partials (SSE hsum order: (a0+a2)+(a1+a3)) -> logits LDS ----
    #pragma unroll
    for (int r = 0; r < 4; ++r)
        #pragma unroll
        for (int s = 0; s < 4; ++s) {
            const float4 a = acc[r][s];
            lg[(4 * gt + r) * (NEXP + 1) + (4 * ge + s)] = (a.x + a.z) + (a.y + a.w);
        }
    __syncthreads();

    // ---- per-token top-6 + softmax + renorm (one thread per token) ----
    if (tid < TB) {
        const int tok = tid;
        float val[TOPK];
        int   idx[TOPK];
        #pragma unroll
        for (int k = 0; k < TOPK; ++k) { val[k] = -3.0e38f; idx[k] = 0; }

        for (int e = 0; e < NEXP; ++e) {
            float cv = lg[tok * (NEXP + 1) + e];
            int   ci = e;
            #pragma unroll
            for (int k = 0; k < TOPK; ++k) {
                if (cv > val[k]) {              // strict > : stable ties, lowest index first
                    const float tv = val[k]; const int ti = idx[k];
                    val[k] = cv; idx[k] = ci;
                    cv = tv; ci = ti;
                }
            }
        }

        const float m = val[0];
        float ex[TOPK];
        float s = 0.f;
        #pragma unroll
        for (int k = 0; k < TOPK; ++k) { ex[k] = expf(val[k] - m); s += ex[k]; }
        float p[TOPK];
        float d = 0.f;
        #pragma unroll
        for (int k = 0; k < TOPK; ++k) { p[k] = ex[k] / s; d += p[k]; }
        d += 1e-20f;

        const int tg = tbase + tok;
        float* oi = out;                              // idx chunk  [NTOK*TOPK]
        float* ow = out + (size_t)NTOK * TOPK;        // weight chunk
        #pragma unroll
        for (int k = 0; k < TOPK; ++k) {
            oi[tg * TOPK + k] = (float)idx[k];
            ow[tg * TOPK + k] = p[k] / d;
        }
    }
}

extern "C" void kernel_launch(void* const* d_in, const int* in_sizes, int n_in,
                              void* d_out, int out_size, void* d_ws, size_t ws_size,
                              hipStream_t stream) {
    const float* x = (const float*)d_in[0];
    const float* w = (const float*)d_in[1];
    float* out = (float*)d_out;
    dim3 grid(NTOK / TB);   // 256 blocks
    dim3 block(256);
    hipLaunchKernelGGL(moe_gate_kernel, grid, block, 0, stream, x, w, out);
}